// Round 1
// baseline (3521.398 us; speedup 1.0000x reference)
//
#include <hip/hip_runtime.h>
#include <math.h>

#define HDIM 512
#define NCH 16          // 15 used channels + 1 pad
#define BETA 25.0f

// channel layout per (point, neuron): c0 = value, c1..c4 = D[a], c5..c14 = H[(a,b) a<=b]
// pair index P: (0,0)=0 (0,1)=1 (0,2)=2 (0,3)=3 (1,1)=4 (1,2)=5 (1,3)=6 (2,2)=7 (2,3)=8 (3,3)=9

__device__ __forceinline__ void softplus_jet(float v, float& phi, float& s, float& pp) {
    float y = BETA * v;
    float e = expf(-fabsf(y));
    float inv = 1.0f / (1.0f + e);
    s = (y >= 0.0f) ? inv : e * inv;          // sigmoid(25 v)  == phi'
    phi = (fmaxf(y, 0.0f) + log1pf(e)) * (1.0f / BETA);
    pp = BETA * s * (1.0f - s);               // phi''
}

// ---------------- layer 0: build initial jet  ----------------
__global__ void layer0_kernel(const float* __restrict__ x, const float* __restrict__ W0,
                              const float* __restrict__ b0, float* __restrict__ Sout, int npts)
{
    int tid = blockIdx.x * 256 + threadIdx.x;
    if (tid >= npts * HDIM) return;
    int p = tid >> 9;
    int n = tid & (HDIM - 1);
    float4 z = *reinterpret_cast<const float4*>(&x[p * 4]);
    float4 w = *reinterpret_cast<const float4*>(&W0[n * 4]);
    float v = w.x * z.x + w.y * z.y + w.z * z.z + w.w * z.w + b0[n];
    float phi, s, pp;
    softplus_jet(v, phi, s, pp);
    float wa[4] = {w.x, w.y, w.z, w.w};
    float o[16];
    o[0] = phi;
#pragma unroll
    for (int a = 0; a < 4; ++a) o[1 + a] = s * wa[a];
    int idx = 5;
#pragma unroll
    for (int a = 0; a < 4; ++a)
#pragma unroll
        for (int b = a; b < 4; ++b) { o[idx] = pp * wa[a] * wa[b]; ++idx; }  // Hv=0 at layer0
    o[15] = 0.0f;
    float* dst = Sout + (size_t)p * (HDIM * NCH) + n * NCH;
#pragma unroll
    for (int q = 0; q < 4; ++q)
        *reinterpret_cast<float4*>(&dst[4 * q]) = make_float4(o[4*q], o[4*q+1], o[4*q+2], o[4*q+3]);
}

// ---------------- hidden layer: jet matmul + activation ----------------
__global__ __launch_bounds__(256) void layer_jet_kernel(
    const float* __restrict__ WT, const float* __restrict__ bias,
    const float* __restrict__ Sin, float* __restrict__ Sout)
{
    int p = blockIdx.x;
    int t = threadIdx.x;
    int n0 = 2 * t;
    const float* sp = Sin + (size_t)p * (HDIM * NCH);

    float acc0[15], acc1[15];
#pragma unroll
    for (int c = 0; c < 15; ++c) { acc0[c] = 0.0f; acc1[c] = 0.0f; }

#pragma unroll 2
    for (int k = 0; k < HDIM; ++k) {
        float2 w = *reinterpret_cast<const float2*>(&WT[k * HDIM + n0]);
        float4 s0 = *reinterpret_cast<const float4*>(&sp[k * NCH + 0]);
        float4 s1 = *reinterpret_cast<const float4*>(&sp[k * NCH + 4]);
        float4 s2 = *reinterpret_cast<const float4*>(&sp[k * NCH + 8]);
        float4 s3 = *reinterpret_cast<const float4*>(&sp[k * NCH + 12]);
        float sv[15] = {s0.x,s0.y,s0.z,s0.w, s1.x,s1.y,s1.z,s1.w,
                        s2.x,s2.y,s2.z,s2.w, s3.x,s3.y,s3.z};
#pragma unroll
        for (int c = 0; c < 15; ++c) {
            acc0[c] = fmaf(w.x, sv[c], acc0[c]);
            acc1[c] = fmaf(w.y, sv[c], acc1[c]);
        }
    }

    float* dst = Sout + (size_t)p * (HDIM * NCH) + n0 * NCH;
#pragma unroll
    for (int half = 0; half < 2; ++half) {
        float* acc = half ? acc1 : acc0;
        int n = n0 + half;
        float v = acc[0] + bias[n];
        float phi, s, pp;
        softplus_jet(v, phi, s, pp);
        float o[16];
        o[0] = phi;
        float d[4];
#pragma unroll
        for (int a = 0; a < 4; ++a) { d[a] = acc[1 + a]; o[1 + a] = s * d[a]; }
        int idx = 5;
#pragma unroll
        for (int a = 0; a < 4; ++a)
#pragma unroll
            for (int b = a; b < 4; ++b) { o[idx] = pp * d[a] * d[b] + s * acc[idx]; ++idx; }
        o[15] = 0.0f;
        float* dh = dst + half * NCH;
#pragma unroll
        for (int q = 0; q < 4; ++q)
            *reinterpret_cast<float4*>(&dh[4 * q]) = make_float4(o[4*q], o[4*q+1], o[4*q+2], o[4*q+3]);
    }
}

// ---------------- final layer + trace ----------------
__global__ __launch_bounds__(256) void trace_kernel(
    const float* __restrict__ Sin, const float* __restrict__ W3,
    const float* __restrict__ b3, float* __restrict__ out, int npts)
{
    int wave = threadIdx.x >> 6;
    int lane = threadIdx.x & 63;
    int p = blockIdx.x * 4 + wave;
    if (p >= npts) return;           // wave-uniform exit
    const float* sp = Sin + (size_t)p * (HDIM * NCH);

    float hu[4][10];
#pragma unroll
    for (int m = 0; m < 4; ++m)
#pragma unroll
        for (int q = 0; q < 10; ++q) hu[m][q] = 0.0f;
    float u4 = 0.0f;

    for (int kk = 0; kk < 8; ++kk) {
        int k = kk * 64 + lane;
        const float* sk = sp + k * NCH;
        float4 s0 = *reinterpret_cast<const float4*>(&sk[0]);
        float4 s1 = *reinterpret_cast<const float4*>(&sk[4]);
        float4 s2 = *reinterpret_cast<const float4*>(&sk[8]);
        float4 s3 = *reinterpret_cast<const float4*>(&sk[12]);
        float hv[10] = {s1.y,s1.z,s1.w, s2.x,s2.y,s2.z,s2.w, s3.x,s3.y,s3.z};
        float w3m[5];
#pragma unroll
        for (int m = 0; m < 5; ++m) w3m[m] = W3[m * HDIM + k];
        u4 = fmaf(w3m[4], s0.x, u4);
#pragma unroll
        for (int m = 0; m < 4; ++m)
#pragma unroll
            for (int q = 0; q < 10; ++q) hu[m][q] = fmaf(w3m[m], hv[q], hu[m][q]);
    }

#pragma unroll
    for (int off = 32; off > 0; off >>= 1) {
#pragma unroll
        for (int m = 0; m < 4; ++m)
#pragma unroll
            for (int q = 0; q < 10; ++q) hu[m][q] += __shfl_xor(hu[m][q], off, 64);
        u4 += __shfl_xor(u4, off, 64);
    }

    if (lane == 0) {
        const int Pm[4][4] = {{0,1,2,3},{1,4,5,6},{2,5,7,8},{3,6,8,9}};
        const int Pd[4] = {0, 4, 7, 9};
#pragma unroll
        for (int i = 0; i < 4; ++i) {
            float t1 = hu[i][Pd[0]] + hu[i][Pd[1]] + hu[i][Pd[2]] + hu[i][Pd[3]];
            float t2 = hu[0][Pm[0][i]] + hu[1][Pm[1][i]] + hu[2][Pm[2][i]] + hu[3][Pm[3][i]];
            out[p * 5 + i] = t1 - t2;
        }
        out[p * 5 + 4] = u4 + b3[4];
    }
}

// ---------------- weight transpose (W1, W2 -> WT row=k) ----------------
__global__ void transpose_kernel(const float* __restrict__ W1, const float* __restrict__ W2,
                                 float* __restrict__ WT1, float* __restrict__ WT2)
{
    int tid = blockIdx.x * 256 + threadIdx.x;
    int m = tid >> 18;                 // 512*512 = 2^18
    int idx = tid & (262144 - 1);
    int k = idx >> 9;
    int n = idx & 511;
    const float* W = m ? W2 : W1;
    float* WT = m ? WT2 : WT1;
    WT[idx] = W[n * HDIM + k];         // WT[k][n] = W[n][k]
}

extern "C" void kernel_launch(void* const* d_in, const int* in_sizes, int n_in,
                              void* d_out, int out_size, void* d_ws, size_t ws_size,
                              hipStream_t stream)
{
    const float* x  = (const float*)d_in[0];
    const float* W0 = (const float*)d_in[1];
    const float* b0 = (const float*)d_in[2];
    const float* W1 = (const float*)d_in[3];
    const float* b1 = (const float*)d_in[4];
    const float* W2 = (const float*)d_in[5];
    const float* b2 = (const float*)d_in[6];
    const float* W3 = (const float*)d_in[7];
    const float* b3 = (const float*)d_in[8];
    float* out = (float*)d_out;

    int B = in_sizes[0] / 4;           // 16384 points

    float* WT1 = (float*)d_ws;                      // 512*512 floats
    float* WT2 = WT1 + HDIM * HDIM;
    float* Sbase = WT2 + HDIM * HDIM;

    size_t remain = ws_size - 2ull * HDIM * HDIM * sizeof(float);
    size_t per_point = 2ull * HDIM * NCH * sizeof(float);   // 64 KB (two state buffers)
    int chunk = (int)(remain / per_point);
    if (chunk > B) chunk = B;
    if (chunk < 1) chunk = 1;

    float* S0 = Sbase;
    float* S1 = Sbase + (size_t)chunk * HDIM * NCH;

    transpose_kernel<<<2048, 256, 0, stream>>>(W1, W2, WT1, WT2);

    for (int base = 0; base < B; base += chunk) {
        int np = (B - base < chunk) ? (B - base) : chunk;
        layer0_kernel<<<(np * HDIM + 255) / 256, 256, 0, stream>>>(x + (size_t)base * 4, W0, b0, S0, np);
        layer_jet_kernel<<<np, 256, 0, stream>>>(WT1, b1, S0, S1);
        layer_jet_kernel<<<np, 256, 0, stream>>>(WT2, b2, S1, S0);
        trace_kernel<<<(np + 3) / 4, 256, 0, stream>>>(S0, W3, b3, out + (size_t)base * 5, np);
    }
}

// Round 3
// 1443.434 us; speedup vs baseline: 2.4396x; 2.4396x over previous
//
#include <hip/hip_runtime.h>
#include <math.h>

#define HDIM 512
#define NCH 16
#define BETA 25.0f
#define KV 1536            // virtual K: hi*hi | hi*lo | lo*hi

typedef unsigned short ushort_t;
typedef __attribute__((ext_vector_type(8))) short short8;
typedef __attribute__((ext_vector_type(4))) float f32x4;

__device__ __forceinline__ ushort_t f2bf(float f) {
    unsigned u = __float_as_uint(f);
    unsigned r = (u + 0x7fff + ((u >> 16) & 1)) >> 16;
    return (ushort_t)r;
}
__device__ __forceinline__ float bf2f(ushort_t b) {
    return __uint_as_float(((unsigned)b) << 16);
}
__device__ __forceinline__ void split_bf(float v, ushort_t& hi, ushort_t& lo) {
    hi = f2bf(v);
    lo = f2bf(v - bf2f(hi));
}

__device__ __forceinline__ void softplus_jet(float v, float& phi, float& s, float& pp) {
    float y = BETA * v;
    float e = expf(-fabsf(y));
    float inv = 1.0f / (1.0f + e);
    s = (y >= 0.0f) ? inv : e * inv;          // sigmoid(25 v) == phi'
    phi = (fmaxf(y, 0.0f) + log1pf(e)) * (1.0f / BETA);
    pp = BETA * s * (1.0f - s);               // phi''
}

__device__ __forceinline__ void gl_lds16(const void* g, void* l) {
    __builtin_amdgcn_global_load_lds(
        (const __attribute__((address_space(1))) unsigned int*)g,
        (__attribute__((address_space(3))) unsigned int*)l, 16, 0, 0);
}

// ---------------- layer 0: build initial jet in A-format (bf16 hi|lo) ----------------
__global__ __launch_bounds__(256) void layer0_jet(
    const float* __restrict__ x, const float* __restrict__ W0,
    const float* __restrict__ b0, ushort_t* __restrict__ A0)
{
    __shared__ ushort_t sm[16 * 1024];   // 32 KB: rows c, cols [hi(512)|lo(512)]
    int p = blockIdx.x, tid = threadIdx.x;
    float4 z = *reinterpret_cast<const float4*>(&x[p * 4]);
#pragma unroll
    for (int half = 0; half < 2; ++half) {
        int n = half * 256 + tid;
        float4 w = *reinterpret_cast<const float4*>(&W0[n * 4]);
        float v = fmaf(w.x, z.x, fmaf(w.y, z.y, fmaf(w.z, z.z, fmaf(w.w, z.w, b0[n]))));
        float phi, s, pp;
        softplus_jet(v, phi, s, pp);
        float wa[4] = {w.x, w.y, w.z, w.w};
        float o[16];
        o[0] = phi;
#pragma unroll
        for (int a = 0; a < 4; ++a) o[1 + a] = s * wa[a];
        int idx = 5;
#pragma unroll
        for (int a = 0; a < 4; ++a)
#pragma unroll
            for (int b = a; b < 4; ++b) { o[idx] = pp * wa[a] * wa[b]; ++idx; }
        o[15] = 0.0f;
#pragma unroll
        for (int c = 0; c < 16; ++c) {
            ushort_t hb, lb;
            split_bf(o[c], hb, lb);
            sm[c * 1024 + n] = hb;
            sm[c * 1024 + 512 + n] = lb;
        }
    }
    __syncthreads();
    uint4* d4 = reinterpret_cast<uint4*>(A0 + (size_t)p * 16 * 1024);
    const uint4* s4 = reinterpret_cast<const uint4*>(sm);
#pragma unroll
    for (int i = 0; i < 8; ++i) d4[tid + 256 * i] = s4[tid + 256 * i];
}

// ---------------- GEMM + fused jet activation epilogue ----------------
// A: [M][1024] bf16 (hi|lo), BT: [512 n][1536 k] bf16 (hi|lo|hi), M = pts*16
// EPI==1: write Anext in A-format. EPI==2: write Sout fp32 [p][n][16c]
template<int EPI>
__global__ __launch_bounds__(256, 2) void gemm_jet(
    const ushort_t* __restrict__ Ag, const ushort_t* __restrict__ BT,
    const float* __restrict__ bias, ushort_t* __restrict__ Anext,
    float* __restrict__ Sout)
{
    __shared__ char smem[32768];
    ushort_t* Al = (ushort_t*)smem;              // [128 m][64 k]
    ushort_t* Bl = (ushort_t*)(smem + 16384);    // [128 n][64 k]
    float*    epi = (float*)smem;                // [64][128] (reused after K loop)

    const int tid = threadIdx.x, wave = tid >> 6, lane = tid & 63;

    // bijective XCD swizzle (m204): consecutive logical blocks -> same XCD
    int nwg = gridDim.x;
    int bid = blockIdx.x;
    int q = nwg >> 3, r = nwg & 7;
    int xcd = bid & 7, i8 = bid >> 3;
    int logical = (xcd < r ? xcd * (q + 1) : r * (q + 1) + (xcd - r) * q) + i8;
    const int m0 = (logical >> 2) * 128;         // 4 n-tiles fastest
    const int n0 = (logical & 3) * 128;
    const int wm = (wave >> 1) * 64, wn = (wave & 1) * 64;

    f32x4 acc[4][4] = {};

    const int sr = wave * 32 + (lane >> 3);      // staging row (+ i*8)
    const int sc = (lane & 7) * 8;               // staging col (elems)

    for (int t = 0; t < KV / 64; ++t) {
        int k0 = t * 64;
        int ka = (k0 < 512) ? k0 : k0 - 512;     // A source col base (hi|lo layout)
        __syncthreads();
#pragma unroll
        for (int i = 0; i < 4; ++i)
            gl_lds16(Ag + (size_t)(m0 + sr + i * 8) * 1024 + ka + sc,
                     Al + (wave * 32 + i * 8) * 64);
#pragma unroll
        for (int i = 0; i < 4; ++i)
            gl_lds16(BT + (size_t)(n0 + sr + i * 8) * KV + k0 + sc,
                     Bl + (wave * 32 + i * 8) * 64);
        __syncthreads();
        const int rA = lane & 15;
#pragma unroll
        for (int kk = 0; kk < 2; ++kk) {
            const int kc = kk * 32 + (lane >> 4) * 8;
            short8 af[4], bf[4];
#pragma unroll
            for (int mi = 0; mi < 4; ++mi)
                af[mi] = *(const short8*)&Al[(wm + mi * 16 + rA) * 64 + kc];
#pragma unroll
            for (int ni = 0; ni < 4; ++ni)
                bf[ni] = *(const short8*)&Bl[(wn + ni * 16 + rA) * 64 + kc];
#pragma unroll
            for (int mi = 0; mi < 4; ++mi)
#pragma unroll
                for (int ni = 0; ni < 4; ++ni)
                    acc[mi][ni] = __builtin_amdgcn_mfma_f32_16x16x32_bf16(
                        af[mi], bf[ni], acc[mi][ni], 0, 0, 0);
        }
    }

    // ---- epilogue: LDS transpose per 64-row half, fused activation ----
    const int pl = lane & 15, ph = lane >> 4;
#pragma unroll
    for (int h = 0; h < 2; ++h) {
        __syncthreads();
        if ((wave >> 1) == h) {
#pragma unroll
            for (int mi = 0; mi < 4; ++mi)
#pragma unroll
                for (int ni = 0; ni < 4; ++ni)
#pragma unroll
                    for (int rr = 0; rr < 4; ++rr)
                        epi[(mi * 16 + ph * 4 + rr) * 128 + wn + ni * 16 + pl] = acc[mi][ni][rr];
        }
        __syncthreads();
#pragma unroll
        for (int rep = 0; rep < 2; ++rep) {
            int idx = rep * 256 + tid;
            int n = idx & 127, pq = idx >> 7;         // pq in [0,4)
            const float* vp = &epi[pq * 16 * 128 + n];
            float v[15];
#pragma unroll
            for (int c = 0; c < 15; ++c) v[c] = vp[c * 128];
            float val = v[0] + bias[n0 + n];
            float phi, s, pp;
            softplus_jet(val, phi, s, pp);
            float o[16];
            o[0] = phi;
            float d[4];
#pragma unroll
            for (int a = 0; a < 4; ++a) { d[a] = v[1 + a]; o[1 + a] = s * d[a]; }
            int ix = 5;
#pragma unroll
            for (int a = 0; a < 4; ++a)
#pragma unroll
                for (int b = a; b < 4; ++b) { o[ix] = pp * d[a] * d[b] + s * v[ix]; ++ix; }
            o[15] = 0.0f;
            size_t prow = (size_t)(m0 >> 4) + h * 4 + pq;   // chunk-local point
            if (EPI == 1) {
                size_t rb = prow * 16 * 1024;
#pragma unroll
                for (int c = 0; c < 16; ++c) {
                    ushort_t hb, lb;
                    split_bf(o[c], hb, lb);
                    Anext[rb + (size_t)c * 1024 + n0 + n] = hb;
                    Anext[rb + (size_t)c * 1024 + 512 + n0 + n] = lb;
                }
            } else {
                float4* op = reinterpret_cast<float4*>(Sout + ((size_t)prow * 512 + n0 + n) * 16);
#pragma unroll
                for (int qq = 0; qq < 4; ++qq)
                    op[qq] = make_float4(o[4*qq], o[4*qq+1], o[4*qq+2], o[4*qq+3]);
            }
        }
    }
}

// ---------------- final layer + trace (validated round-1 kernel) ----------------
__global__ __launch_bounds__(256) void trace_kernel(
    const float* __restrict__ Sin, const float* __restrict__ W3,
    const float* __restrict__ b3, float* __restrict__ out, int npts)
{
    int wave = threadIdx.x >> 6;
    int lane = threadIdx.x & 63;
    int p = blockIdx.x * 4 + wave;
    if (p >= npts) return;
    const float* sp = Sin + (size_t)p * (HDIM * NCH);

    float hu[4][10];
#pragma unroll
    for (int m = 0; m < 4; ++m)
#pragma unroll
        for (int qq = 0; qq < 10; ++qq) hu[m][qq] = 0.0f;
    float u4 = 0.0f;

    for (int kk = 0; kk < 8; ++kk) {
        int k = kk * 64 + lane;
        const float* sk = sp + k * NCH;
        float4 s0 = *reinterpret_cast<const float4*>(&sk[0]);
        float4 s1 = *reinterpret_cast<const float4*>(&sk[4]);
        float4 s2 = *reinterpret_cast<const float4*>(&sk[8]);
        float4 s3 = *reinterpret_cast<const float4*>(&sk[12]);
        float hv[10] = {s1.y,s1.z,s1.w, s2.x,s2.y,s2.z,s2.w, s3.x,s3.y,s3.z};
        float w3m[5];
#pragma unroll
        for (int m = 0; m < 5; ++m) w3m[m] = W3[m * HDIM + k];
        u4 = fmaf(w3m[4], s0.x, u4);
#pragma unroll
        for (int m = 0; m < 4; ++m)
#pragma unroll
            for (int qq = 0; qq < 10; ++qq) hu[m][qq] = fmaf(w3m[m], hv[qq], hu[m][qq]);
    }

#pragma unroll
    for (int off = 32; off > 0; off >>= 1) {
#pragma unroll
        for (int m = 0; m < 4; ++m)
#pragma unroll
            for (int qq = 0; qq < 10; ++qq) hu[m][qq] += __shfl_xor(hu[m][qq], off, 64);
        u4 += __shfl_xor(u4, off, 64);
    }

    if (lane == 0) {
        const int Pm[4][4] = {{0,1,2,3},{1,4,5,6},{2,5,7,8},{3,6,8,9}};
        const int Pd[4] = {0, 4, 7, 9};
#pragma unroll
        for (int i = 0; i < 4; ++i) {
            float t1 = hu[i][Pd[0]] + hu[i][Pd[1]] + hu[i][Pd[2]] + hu[i][Pd[3]];
            float t2 = hu[0][Pm[0][i]] + hu[1][Pm[1][i]] + hu[2][Pm[2][i]] + hu[3][Pm[3][i]];
            out[p * 5 + i] = t1 - t2;
        }
        out[p * 5 + 4] = u4 + b3[4];
    }
}

// ---------------- weight prep: W (n,k) -> BT[n][hi|lo|hi] bf16 ----------------
__global__ void prep_B(const float* __restrict__ W1, const float* __restrict__ W2,
                       ushort_t* __restrict__ BT1, ushort_t* __restrict__ BT2)
{
    int tid = blockIdx.x * 256 + threadIdx.x;   // 2*512*512 total
    int l = tid >> 18;
    int i = tid & 262143;
    int n = i >> 9, k = i & 511;
    const float* W = l ? W2 : W1;
    ushort_t* BT = l ? BT2 : BT1;
    float v = W[i];
    ushort_t hb, lb;
    split_bf(v, hb, lb);
    size_t rr = (size_t)n * KV;
    BT[rr + k] = hb;
    BT[rr + 512 + k] = lb;
    BT[rr + 1024 + k] = hb;
}

extern "C" void kernel_launch(void* const* d_in, const int* in_sizes, int n_in,
                              void* d_out, int out_size, void* d_ws, size_t ws_size,
                              hipStream_t stream)
{
    const float* x  = (const float*)d_in[0];
    const float* W0 = (const float*)d_in[1];
    const float* b0 = (const float*)d_in[2];
    const float* W1 = (const float*)d_in[3];
    const float* b1 = (const float*)d_in[4];
    const float* W2 = (const float*)d_in[5];
    const float* b2 = (const float*)d_in[6];
    const float* W3 = (const float*)d_in[7];
    const float* b3 = (const float*)d_in[8];
    float* out = (float*)d_out;

    int B = in_sizes[0] / 4;                    // 16384 points

    ushort_t* BT1 = (ushort_t*)d_ws;            // 512*1536 bf16
    ushort_t* BT2 = BT1 + 512 * KV;
    char* bufbase = (char*)(BT2 + 512 * KV);

    size_t avail = ws_size - 2ull * 512 * KV * sizeof(ushort_t);
    size_t per_pt = 2ull * 32768;               // A0/A1 buffers, 32KB each per point
    int Pc = (int)(avail / per_pt) & ~7;
    if (Pc > 4096) Pc = 4096;
    if (Pc < 8) Pc = 8;

    ushort_t* A0 = (ushort_t*)bufbase;                        // Pc*16*1024
    ushort_t* A1 = (ushort_t*)(bufbase + (size_t)Pc * 32768);
    float* S2 = (float*)A0;                                   // reuse A0 after GEMM1

    prep_B<<<2048, 256, 0, stream>>>(W1, W2, BT1, BT2);

    for (int base = 0; base < B; base += Pc) {
        int np = (B - base < Pc) ? (B - base) : Pc;
        layer0_jet<<<np, 256, 0, stream>>>(x + (size_t)base * 4, W0, b0, A0);
        int nwg = (np / 8) * 4;                 // (M/128) * (N/128)
        gemm_jet<1><<<nwg, 256, 0, stream>>>(A0, BT1, b1, A1, nullptr);
        gemm_jet<2><<<nwg, 256, 0, stream>>>(A1, BT2, b2, nullptr, S2);
        trace_kernel<<<(np + 3) / 4, 256, 0, stream>>>(S2, W3, b3, out + (size_t)base * 5, np);
    }
}

// Round 5
// 1391.283 us; speedup vs baseline: 2.5310x; 1.0375x over previous
//
#include <hip/hip_runtime.h>
#include <math.h>

#define HDIM 512
#define NCH 16
#define BETA 25.0f
#define KV 1536            // virtual K: hi*hi | hi*lo | lo*hi
#define NKH 48             // KV/32 K-halves

typedef unsigned short ushort_t;
typedef __attribute__((ext_vector_type(8))) short short8;
typedef __attribute__((ext_vector_type(4))) float f32x4;

__device__ __forceinline__ ushort_t f2bf(float f) {
    unsigned u = __float_as_uint(f);
    unsigned r = (u + 0x7fff + ((u >> 16) & 1)) >> 16;
    return (ushort_t)r;
}
__device__ __forceinline__ float bf2f(ushort_t b) {
    return __uint_as_float(((unsigned)b) << 16);
}
__device__ __forceinline__ void split_bf(float v, ushort_t& hi, ushort_t& lo) {
    hi = f2bf(v);
    lo = f2bf(v - bf2f(hi));
}

__device__ __forceinline__ void softplus_jet(float v, float& phi, float& s, float& pp) {
    float y = BETA * v;
    float e = expf(-fabsf(y));
    float inv = 1.0f / (1.0f + e);
    s = (y >= 0.0f) ? inv : e * inv;          // sigmoid(25 v) == phi'
    phi = (fmaxf(y, 0.0f) + log1pf(e)) * (1.0f / BETA);
    pp = BETA * s * (1.0f - s);               // phi''
}

__device__ __forceinline__ void gl_lds16(const void* g, void* l) {
    __builtin_amdgcn_global_load_lds(
        (const __attribute__((address_space(1))) unsigned int*)g,
        (__attribute__((address_space(3))) unsigned int*)l, 16, 0, 0);
}

// ---------------- layer 0: build initial jet in A-format (bf16 hi|lo) ----------------
__global__ __launch_bounds__(256) void layer0_jet(
    const float* __restrict__ x, const float* __restrict__ W0,
    const float* __restrict__ b0, ushort_t* __restrict__ A0)
{
    __shared__ ushort_t sm[16 * 1024];   // 32 KB: rows c, cols [hi(512)|lo(512)]
    int p = blockIdx.x, tid = threadIdx.x;
    float4 z = *reinterpret_cast<const float4*>(&x[p * 4]);
#pragma unroll
    for (int half = 0; half < 2; ++half) {
        int n = half * 256 + tid;
        float4 w = *reinterpret_cast<const float4*>(&W0[n * 4]);
        float v = fmaf(w.x, z.x, fmaf(w.y, z.y, fmaf(w.z, z.z, fmaf(w.w, z.w, b0[n]))));
        float phi, s, pp;
        softplus_jet(v, phi, s, pp);
        float wa[4] = {w.x, w.y, w.z, w.w};
        float o[16];
        o[0] = phi;
#pragma unroll
        for (int a = 0; a < 4; ++a) o[1 + a] = s * wa[a];
        int idx = 5;
#pragma unroll
        for (int a = 0; a < 4; ++a)
#pragma unroll
            for (int b = a; b < 4; ++b) { o[idx] = pp * wa[a] * wa[b]; ++idx; }
        o[15] = 0.0f;
#pragma unroll
        for (int c = 0; c < 16; ++c) {
            ushort_t hb, lb;
            split_bf(o[c], hb, lb);
            sm[c * 1024 + n] = hb;
            sm[c * 1024 + 512 + n] = lb;
        }
    }
    __syncthreads();
    uint4* d4 = reinterpret_cast<uint4*>(A0 + (size_t)p * 16 * 1024);
    const uint4* s4 = reinterpret_cast<const uint4*>(sm);
#pragma unroll
    for (int i = 0; i < 8; ++i) d4[tid + 256 * i] = s4[tid + 256 * i];
}

// ---------------- 256x256 8-phase GEMM + fused jet activation epilogue ----------------
// A: [M][1024] bf16 (hi|lo), BT: [512 n][1536 k] bf16 (hi|lo|hi), M = pts*16
// LDS: 4-slot ring of K-half subtiles [256][32] per operand (64 B rows -> conflict-free b128)
// Derived-waits: K-half g staged 5-6 phases before first read; vmcnt(8) at end of
// every odd phase = 4 phases x 2 loads issued after the needed stage (FIFO ledger);
// barrier between wait and read gives cross-wave visibility. Stage targets a slot
// whose last read was lgkmcnt(0)-drained one phase earlier. No vmcnt(0) in-loop (T4).
template<int EPI>
__global__ __launch_bounds__(512, 2) void gemm_jet8(
    const ushort_t* __restrict__ Ag, const ushort_t* __restrict__ BT,
    const float* __restrict__ bias, ushort_t* __restrict__ Anext,
    float* __restrict__ Sout)
{
    __shared__ char smem[131072];
    ushort_t* Asl = (ushort_t*)smem;             // 4 slots x [256][32] = 64 KB
    ushort_t* Bsl = (ushort_t*)(smem + 65536);   // 4 slots x [256][32] = 64 KB
    float*    epi = (float*)smem;                // [128][256] fp32 (reused after K loop)

    const int tid = threadIdx.x;
    const int wave = tid >> 6, lane = tid & 63;
    const int wr = wave >> 2, wc = wave & 3;     // 2M x 4N wave grid

    // bijective XCD swizzle (m204): n-tile fastest so A-panel pairs share an XCD L2
    int nwg = gridDim.x, bid = blockIdx.x;
    int q = nwg >> 3, r = nwg & 7;
    int xcd = bid & 7, i8 = bid >> 3;
    int logical = (xcd < r ? xcd * (q + 1) : r * (q + 1) + (xcd - r) * q) + i8;
    const int mt = logical >> 1;
    const int m0 = mt * 256;
    const int n0 = (logical & 1) * 256;

    // staging thread mapping: wave-round covers 16 rows x 64 B (linear in LDS)
    const int s_w2 = wave * 2;
    const int s_r  = lane >> 2;                  // row within 16
    const int s_c  = (lane & 3) * 8;             // col elems within 32

    f32x4 acc[8][4] = {};

    auto stageA = [&](int g) {
        if (g >= NKH) g -= NKH;                  // wrap (tail stages: harmless re-reads)
        const int slot = g & 3;
        int k0 = g * 32;
        int ka = (k0 < 512) ? k0 : k0 - 512;     // A hi|lo source col
#pragma unroll
        for (int rr = 0; rr < 2; ++rr) {
            int row = (s_w2 + rr) * 16 + s_r;
            gl_lds16(Ag + (size_t)(m0 + row) * 1024 + ka + s_c,
                     Asl + slot * 8192 + (s_w2 + rr) * 512);
        }
    };
    auto stageB = [&](int g) {
        if (g >= NKH) g -= NKH;
        const int slot = g & 3;
        int k0 = g * 32;
#pragma unroll
        for (int rr = 0; rr < 2; ++rr) {
            int row = (s_w2 + rr) * 16 + s_r;
            gl_lds16(BT + (size_t)(n0 + row) * KV + k0 + s_c,
                     Bsl + slot * 8192 + (s_w2 + rr) * 512);
        }
    };

    // prologue: stage K-halves 0,1,2 (A,B interleaved; 12 loads/thread)
    stageA(0); stageB(0); stageA(1); stageB(1); stageA(2); stageB(2);
    asm volatile("s_waitcnt vmcnt(8)" ::: "memory");   // K-half 0 complete
    __builtin_amdgcn_s_barrier();
    asm volatile("" ::: "memory");

    const int rA = lane & 15;
    const int kc = (lane >> 4) * 8;

    for (int j = 0; j < 12; ++j) {
        short8 bf[4];
#pragma unroll
        for (int p = 0; p < 8; ++p) {
            const int kh = p >> 1, qm = p & 1;   // K-half-local + m-quadrant
            const int slot = kh;                 // (4j+kh)&3 == kh
            const ushort_t* Ab = Asl + slot * 8192;
            const ushort_t* Bb = Bsl + slot * 8192;
            short8 af[4];
#pragma unroll
            for (int mi = 0; mi < 4; ++mi)
                af[mi] = *(const short8*)&Ab[(wr * 128 + qm * 64 + mi * 16 + rA) * 32 + kc];
            if (qm == 0) {
#pragma unroll
                for (int ni = 0; ni < 4; ++ni)
                    bf[ni] = *(const short8*)&Bb[(wc * 64 + ni * 16 + rA) * 32 + kc];
            }
            // stage one operand-half (target slot last read one phase ago)
            if (qm == 0) stageA(4 * j + 3 + kh); else stageB(4 * j + 3 + kh);
            if (qm == 1) asm volatile("s_waitcnt vmcnt(8)" ::: "memory");
            asm volatile("" ::: "memory");
            __builtin_amdgcn_s_barrier();
            asm volatile("s_waitcnt lgkmcnt(0)" ::: "memory");
            __builtin_amdgcn_sched_barrier(0);   // rule 18
            __builtin_amdgcn_s_setprio(1);
#pragma unroll
            for (int mi = 0; mi < 4; ++mi)
#pragma unroll
                for (int ni = 0; ni < 4; ++ni)
                    acc[qm * 4 + mi][ni] = __builtin_amdgcn_mfma_f32_16x16x32_bf16(
                        af[mi], bf[ni], acc[qm * 4 + mi][ni], 0, 0, 0);
            __builtin_amdgcn_s_setprio(0);
            asm volatile("" ::: "memory");
            __builtin_amdgcn_s_barrier();
            asm volatile("" ::: "memory");
        }
    }

    // drain wrapped tail stages before repurposing LDS
    asm volatile("s_waitcnt vmcnt(0)" ::: "memory");
    __builtin_amdgcn_s_barrier();
    asm volatile("" ::: "memory");

    // ---- epilogue: two 128-row passes, LDS transpose + fused activation ----
    const int pl = lane & 15, ph = lane >> 4;
#pragma unroll
    for (int h = 0; h < 2; ++h) {
        if (h) { asm volatile("" ::: "memory"); __builtin_amdgcn_s_barrier(); }
        if (wr == h) {
#pragma unroll
            for (int am = 0; am < 8; ++am)
#pragma unroll
                for (int ni = 0; ni < 4; ++ni)
#pragma unroll
                    for (int rr = 0; rr < 4; ++rr)
                        epi[(am * 16 + ph * 4 + rr) * 256 + wc * 64 + ni * 16 + pl] = acc[am][ni][rr];
        }
        asm volatile("" ::: "memory");
        __builtin_amdgcn_s_barrier();
        asm volatile("" ::: "memory");
#pragma unroll
        for (int rep = 0; rep < 4; ++rep) {
            int idx = rep * 512 + tid;
            int n = idx & 255, pq = idx >> 8;        // pq in [0,8)
            const float* vp = &epi[pq * 16 * 256 + n];
            float v[15];
#pragma unroll
            for (int c = 0; c < 15; ++c) v[c] = vp[c * 256];
            float val = v[0] + bias[n0 + n];
            float phi, s, pp;
            softplus_jet(val, phi, s, pp);
            float o[16];
            o[0] = phi;
            float d[4];
#pragma unroll
            for (int a = 0; a < 4; ++a) { d[a] = v[1 + a]; o[1 + a] = s * d[a]; }
            int ix = 5;
#pragma unroll
            for (int a = 0; a < 4; ++a)
#pragma unroll
                for (int b = a; b < 4; ++b) { o[ix] = pp * d[a] * d[b] + s * v[ix]; ++ix; }
            o[15] = 0.0f;
            size_t prow = (size_t)mt * 16 + h * 8 + pq;   // chunk-local point
            if (EPI == 1) {
                size_t rb = prow * 16 * 1024;
#pragma unroll
                for (int c = 0; c < 16; ++c) {
                    ushort_t hb, lb;
                    split_bf(o[c], hb, lb);
                    Anext[rb + (size_t)c * 1024 + n0 + n] = hb;
                    Anext[rb + (size_t)c * 1024 + 512 + n0 + n] = lb;
                }
            } else {
                float4* op = reinterpret_cast<float4*>(Sout + ((size_t)prow * 512 + n0 + n) * 16);
#pragma unroll
                for (int qq = 0; qq < 4; ++qq)
                    op[qq] = make_float4(o[4*qq], o[4*qq+1], o[4*qq+2], o[4*qq+3]);
            }
        }
    }
}

// ---------------- final layer + trace (validated) ----------------
__global__ __launch_bounds__(256) void trace_kernel(
    const float* __restrict__ Sin, const float* __restrict__ W3,
    const float* __restrict__ b3, float* __restrict__ out, int npts)
{
    int wave = threadIdx.x >> 6;
    int lane = threadIdx.x & 63;
    int p = blockIdx.x * 4 + wave;
    if (p >= npts) return;
    const float* sp = Sin + (size_t)p * (HDIM * NCH);

    float hu[4][10];
#pragma unroll
    for (int m = 0; m < 4; ++m)
#pragma unroll
        for (int qq = 0; qq < 10; ++qq) hu[m][qq] = 0.0f;
    float u4 = 0.0f;

    for (int kk = 0; kk < 8; ++kk) {
        int k = kk * 64 + lane;
        const float* sk = sp + k * NCH;
        float4 s0 = *reinterpret_cast<const float4*>(&sk[0]);
        float4 s1 = *reinterpret_cast<const float4*>(&sk[4]);
        float4 s2 = *reinterpret_cast<const float4*>(&sk[8]);
        float4 s3 = *reinterpret_cast<const float4*>(&sk[12]);
        float hv[10] = {s1.y,s1.z,s1.w, s2.x,s2.y,s2.z,s2.w, s3.x,s3.y,s3.z};
        float w3m[5];
#pragma unroll
        for (int m = 0; m < 5; ++m) w3m[m] = W3[m * HDIM + k];
        u4 = fmaf(w3m[4], s0.x, u4);
#pragma unroll
        for (int m = 0; m < 4; ++m)
#pragma unroll
            for (int qq = 0; qq < 10; ++qq) hu[m][qq] = fmaf(w3m[m], hv[qq], hu[m][qq]);
    }

#pragma unroll
    for (int off = 32; off > 0; off >>= 1) {
#pragma unroll
        for (int m = 0; m < 4; ++m)
#pragma unroll
            for (int qq = 0; qq < 10; ++qq) hu[m][qq] += __shfl_xor(hu[m][qq], off, 64);
        u4 += __shfl_xor(u4, off, 64);
    }

    if (lane == 0) {
        const int Pm[4][4] = {{0,1,2,3},{1,4,5,6},{2,5,7,8},{3,6,8,9}};
        const int Pd[4] = {0, 4, 7, 9};
#pragma unroll
        for (int i = 0; i < 4; ++i) {
            float t1 = hu[i][Pd[0]] + hu[i][Pd[1]] + hu[i][Pd[2]] + hu[i][Pd[3]];
            float t2 = hu[0][Pm[0][i]] + hu[1][Pm[1][i]] + hu[2][Pm[2][i]] + hu[3][Pm[3][i]];
            out[p * 5 + i] = t1 - t2;
        }
        out[p * 5 + 4] = u4 + b3[4];
    }
}

// ---------------- weight prep: W (n,k) -> BT[n][hi|lo|hi] bf16 ----------------
__global__ void prep_B(const float* __restrict__ W1, const float* __restrict__ W2,
                       ushort_t* __restrict__ BT1, ushort_t* __restrict__ BT2)
{
    int tid = blockIdx.x * 256 + threadIdx.x;   // 2*512*512 total
    int l = tid >> 18;
    int i = tid & 262143;
    int n = i >> 9, k = i & 511;
    const float* W = l ? W2 : W1;
    ushort_t* BT = l ? BT2 : BT1;
    float v = W[i];
    ushort_t hb, lb;
    split_bf(v, hb, lb);
    size_t rr = (size_t)n * KV;
    BT[rr + k] = hb;
    BT[rr + 512 + k] = lb;
    BT[rr + 1024 + k] = hb;
}

extern "C" void kernel_launch(void* const* d_in, const int* in_sizes, int n_in,
                              void* d_out, int out_size, void* d_ws, size_t ws_size,
                              hipStream_t stream)
{
    const float* x  = (const float*)d_in[0];
    const float* W0 = (const float*)d_in[1];
    const float* b0 = (const float*)d_in[2];
    const float* W1 = (const float*)d_in[3];
    const float* b1 = (const float*)d_in[4];
    const float* W2 = (const float*)d_in[5];
    const float* b2 = (const float*)d_in[6];
    const float* W3 = (const float*)d_in[7];
    const float* b3 = (const float*)d_in[8];
    float* out = (float*)d_out;

    int B = in_sizes[0] / 4;                    // 16384 points

    ushort_t* BT1 = (ushort_t*)d_ws;            // 512*1536 bf16
    ushort_t* BT2 = BT1 + 512 * KV;
    char* bufbase = (char*)(BT2 + 512 * KV);

    size_t avail = ws_size - 2ull * 512 * KV * sizeof(ushort_t);
    size_t per_pt = 2ull * 32768;               // A0/A1 buffers, 32KB each per point
    int Pc = (int)(avail / per_pt) & ~15;       // multiple of 16 (BM=256 = 16 points)
    if (Pc > 16384) Pc = 16384;
    if (Pc < 16) Pc = 16;

    ushort_t* A0 = (ushort_t*)bufbase;                        // Pc*16*1024
    ushort_t* A1 = (ushort_t*)(bufbase + (size_t)Pc * 32768);
    float* S2 = (float*)A0;                                   // reuse A0 after GEMM1

    prep_B<<<2048, 256, 0, stream>>>(W1, W2, BT1, BT2);

    for (int base = 0; base < B; base += Pc) {
        int np = (B - base < Pc) ? (B - base) : Pc;
        layer0_jet<<<np, 256, 0, stream>>>(x + (size_t)base * 4, W0, b0, A0);
        int nwg = (np / 16) * 2;                // (M/256) * (N/256)
        gemm_jet8<1><<<nwg, 512, 0, stream>>>(A0, BT1, b1, A1, nullptr);
        gemm_jet8<2><<<nwg, 512, 0, stream>>>(A1, BT2, b2, nullptr, S2);
        trace_kernel<<<(np + 3) / 4, 256, 0, stream>>>(S2, W3, b3, out + (size_t)base * 5, np);
    }
}

// Round 6
// 1316.229 us; speedup vs baseline: 2.6754x; 1.0570x over previous
//
#include <hip/hip_runtime.h>
#include <math.h>

#define HDIM 512
#define NCH 16
#define BETA 25.0f
#define KV 1536            // virtual K: hi*hi | hi*lo | lo*hi
#define NKH 48             // KV/32 K-halves

typedef unsigned short ushort_t;
typedef __attribute__((ext_vector_type(8))) short short8;
typedef __attribute__((ext_vector_type(4))) float f32x4;

__device__ __forceinline__ ushort_t f2bf(float f) {
    unsigned u = __float_as_uint(f);
    unsigned r = (u + 0x7fff + ((u >> 16) & 1)) >> 16;
    return (ushort_t)r;
}
__device__ __forceinline__ float bf2f(ushort_t b) {
    return __uint_as_float(((unsigned)b) << 16);
}
__device__ __forceinline__ void split_bf(float v, ushort_t& hi, ushort_t& lo) {
    hi = f2bf(v);
    lo = f2bf(v - bf2f(hi));
}

__device__ __forceinline__ void softplus_jet(float v, float& phi, float& s, float& pp) {
    float y = BETA * v;
    float e = expf(-fabsf(y));
    float inv = 1.0f / (1.0f + e);
    s = (y >= 0.0f) ? inv : e * inv;          // sigmoid(25 v) == phi'
    phi = (fmaxf(y, 0.0f) + log1pf(e)) * (1.0f / BETA);
    pp = BETA * s * (1.0f - s);               // phi''
}

__device__ __forceinline__ void gl_lds16(const void* g, void* l) {
    __builtin_amdgcn_global_load_lds(
        (const __attribute__((address_space(1))) unsigned int*)g,
        (__attribute__((address_space(3))) unsigned int*)l, 16, 0, 0);
}

// ---------------- layer 0: build initial jet in A-format (bf16 hi|lo) ----------------
__global__ __launch_bounds__(256) void layer0_jet(
    const float* __restrict__ x, const float* __restrict__ W0,
    const float* __restrict__ b0, ushort_t* __restrict__ A0)
{
    __shared__ ushort_t sm[16 * 1024];   // 32 KB: rows c, cols [hi(512)|lo(512)]
    int p = blockIdx.x, tid = threadIdx.x;
    float4 z = *reinterpret_cast<const float4*>(&x[p * 4]);
#pragma unroll
    for (int half = 0; half < 2; ++half) {
        int n = half * 256 + tid;
        float4 w = *reinterpret_cast<const float4*>(&W0[n * 4]);
        float v = fmaf(w.x, z.x, fmaf(w.y, z.y, fmaf(w.z, z.z, fmaf(w.w, z.w, b0[n]))));
        float phi, s, pp;
        softplus_jet(v, phi, s, pp);
        float wa[4] = {w.x, w.y, w.z, w.w};
        float o[16];
        o[0] = phi;
#pragma unroll
        for (int a = 0; a < 4; ++a) o[1 + a] = s * wa[a];
        int idx = 5;
#pragma unroll
        for (int a = 0; a < 4; ++a)
#pragma unroll
            for (int b = a; b < 4; ++b) { o[idx] = pp * wa[a] * wa[b]; ++idx; }
        o[15] = 0.0f;
#pragma unroll
        for (int c = 0; c < 16; ++c) {
            ushort_t hb, lb;
            split_bf(o[c], hb, lb);
            sm[c * 1024 + n] = hb;
            sm[c * 1024 + 512 + n] = lb;
        }
    }
    __syncthreads();
    uint4* d4 = reinterpret_cast<uint4*>(A0 + (size_t)p * 16 * 1024);
    const uint4* s4 = reinterpret_cast<const uint4*>(sm);
#pragma unroll
    for (int i = 0; i < 8; ++i) d4[tid + 256 * i] = s4[tid + 256 * i];
}

// ---------------- 256x256 GEMM, reg-dbuf pipeline + fused jet epilogue ----------------
// A: [M][1024] bf16 (hi|lo), BT: [512 n][1536 k] bf16 (hi|lo|hi), M = pts*16
// LDS: ring-4 of K-half subtiles [256][32] per operand, 16B-chunk swizzled:
//   chunk c of row r stored at linear slot (c + (r>>1))&3 (realized by permuting the
//   GLOBAL source per lane; LDS dest stays linear per gl_lds rules). Fragment reads
//   use the matching swizzled offset -> 2-way-max bank aliasing (free).
// Pipeline: reads at phase t fetch fragments for phase t+1 (af statically double-
// buffered across the 2-phase unroll; bf reloaded post-MFMA when dead). Wait before
// MFMA is the compiler's counted lgkmcnt (only next-phase reads outstanding).
// Stage ledger: half g A-staged @phase 2(g-3), B @2(g-3)+1, 2 loads/thread/phase;
// first read of half g at top of phase 2g-1 -> vmcnt(6) each phase guarantees it.
template<int EPI>
__global__ __launch_bounds__(512, 2) void gemm_jet8(
    const ushort_t* __restrict__ Ag, const ushort_t* __restrict__ BT,
    const float* __restrict__ bias, ushort_t* __restrict__ Anext,
    float* __restrict__ Sout)
{
    __shared__ char smem[131072];
    ushort_t* Asl = (ushort_t*)smem;             // 4 slots x [256][32] = 64 KB
    ushort_t* Bsl = (ushort_t*)(smem + 65536);   // 4 slots x [256][32] = 64 KB
    float*    epi = (float*)smem;                // [128][256] fp32 (reused after K loop)

    const int tid = threadIdx.x;
    const int wave = tid >> 6, lane = tid & 63;
    const int wr = wave >> 2, wc = wave & 3;     // 2M x 4N wave grid

    // bijective XCD swizzle (m204)
    int nwg = gridDim.x, bid = blockIdx.x;
    int q = nwg >> 3, r = nwg & 7;
    int xcd = bid & 7, i8 = bid >> 3;
    int logical = (xcd < r ? xcd * (q + 1) : r * (q + 1) + (xcd - r) * q) + i8;
    const int mt = logical >> 1;
    const int m0 = mt * 256;
    const int n0 = (logical & 1) * 256;

    // staging: lane l covers row (s_w2+rr)*16 + (l>>2), linear 16B slot (l&3);
    // source chunk permuted so stored layout is the swizzled one.
    const int s_w2 = wave * 2;
    const int s_row = lane >> 2;
    const int s_c  = (((lane & 3) - ((lane >> 3) & 3)) & 3) * 8;

    f32x4 acc[8][4] = {};

    auto stageA = [&](int g) {
        if (g >= NKH) g -= NKH;                  // wrap: harmless identical re-stage
        const int slot = g & 3;
        int k0 = g * 32;
        int ka = (k0 < 512) ? k0 : k0 - 512;     // A hi|lo source col
#pragma unroll
        for (int rr = 0; rr < 2; ++rr) {
            int row = (s_w2 + rr) * 16 + s_row;
            gl_lds16(Ag + (size_t)(m0 + row) * 1024 + ka + s_c,
                     Asl + slot * 8192 + (s_w2 + rr) * 512);
        }
    };
    auto stageB = [&](int g) {
        if (g >= NKH) g -= NKH;
        const int slot = g & 3;
        int k0 = g * 32;
#pragma unroll
        for (int rr = 0; rr < 2; ++rr) {
            int row = (s_w2 + rr) * 16 + s_row;
            gl_lds16(BT + (size_t)(n0 + row) * KV + k0 + s_c,
                     Bsl + slot * 8192 + (s_w2 + rr) * 512);
        }
    };

    // swizzled fragment read offset (elems): row rA, k-chunk (lane>>4)
    const int rA = lane & 15;
    const int rd = rA * 32 + ((((lane >> 4) + (rA >> 1)) & 3) * 8);

    // prologue: stage halves 0,1,2 (A,B interleaved: 12 loads/thread)
    stageA(0); stageB(0); stageA(1); stageB(1); stageA(2); stageB(2);
    asm volatile("s_waitcnt vmcnt(8)" ::: "memory");   // half 0 complete
    __builtin_amdgcn_s_barrier();
    asm volatile("" ::: "memory");

    short8 afA[4], afB[4], bfr[4];
#pragma unroll
    for (int mi = 0; mi < 4; ++mi)
        afA[mi] = *(const short8*)&Asl[(wr * 128 + mi * 16) * 32 + rd];
#pragma unroll
    for (int ni = 0; ni < 4; ++ni)
        bfr[ni] = *(const short8*)&Bsl[(wc * 64 + ni * 16) * 32 + rd];

#pragma unroll 4
    for (int g = 0; g < NKH; ++g) {
        const int slot = g & 3;
        const int slot1 = (g + 1) & 3;
        // ---- phase qm=0: MFMA(afA,bfr) ; prefetch afB = af(g,1) ; stage A(g+3)
        {
#pragma unroll
            for (int mi = 0; mi < 4; ++mi)
                afB[mi] = *(const short8*)&Asl[slot * 8192 + (wr * 128 + 64 + mi * 16) * 32 + rd];
            stageA(g + 3);
            asm volatile("s_waitcnt vmcnt(6)" ::: "memory");
            __builtin_amdgcn_s_barrier();
            __builtin_amdgcn_s_setprio(1);
#pragma unroll
            for (int mi = 0; mi < 4; ++mi)
#pragma unroll
                for (int ni = 0; ni < 4; ++ni)
                    acc[mi][ni] = __builtin_amdgcn_mfma_f32_16x16x32_bf16(
                        afA[mi], bfr[ni], acc[mi][ni], 0, 0, 0);
            __builtin_amdgcn_s_setprio(0);
            asm volatile("" ::: "memory");
            __builtin_amdgcn_s_barrier();
            asm volatile("" ::: "memory");
        }
        // ---- phase qm=1: MFMA(afB,bfr) ; prefetch afA = af(g+1,0) ; stage B(g+3);
        //      post-MFMA: reload bfr = bf(g+1) (regs dead)
        {
#pragma unroll
            for (int mi = 0; mi < 4; ++mi)
                afA[mi] = *(const short8*)&Asl[slot1 * 8192 + (wr * 128 + mi * 16) * 32 + rd];
            stageB(g + 3);
            asm volatile("s_waitcnt vmcnt(6)" ::: "memory");
            __builtin_amdgcn_s_barrier();
            __builtin_amdgcn_s_setprio(1);
#pragma unroll
            for (int mi = 0; mi < 4; ++mi)
#pragma unroll
                for (int ni = 0; ni < 4; ++ni)
                    acc[4 + mi][ni] = __builtin_amdgcn_mfma_f32_16x16x32_bf16(
                        afB[mi], bfr[ni], acc[4 + mi][ni], 0, 0, 0);
            __builtin_amdgcn_s_setprio(0);
#pragma unroll
            for (int ni = 0; ni < 4; ++ni)
                bfr[ni] = *(const short8*)&Bsl[slot1 * 8192 + (wc * 64 + ni * 16) * 32 + rd];
            asm volatile("" ::: "memory");
            __builtin_amdgcn_s_barrier();
            asm volatile("" ::: "memory");
        }
    }

    // drain before repurposing LDS
    asm volatile("s_waitcnt vmcnt(0) lgkmcnt(0)" ::: "memory");
    __builtin_amdgcn_s_barrier();
    asm volatile("" ::: "memory");

    // ---- epilogue: two 128-row passes, LDS transpose + fused activation ----
    // ds_write col XOR'd by writer-lane ph parity (row>>2 & 1) -> 2-way max.
    const int pl = lane & 15, ph = lane >> 4;
    const int wxor = (ph & 1) << 4;
#pragma unroll
    for (int h = 0; h < 2; ++h) {
        if (h) { asm volatile("" ::: "memory"); __builtin_amdgcn_s_barrier(); }
        if (wr == h) {
#pragma unroll
            for (int am = 0; am < 8; ++am)
#pragma unroll
                for (int ni = 0; ni < 4; ++ni)
#pragma unroll
                    for (int rr = 0; rr < 4; ++rr)
                        epi[(am * 16 + ph * 4 + rr) * 256 + ((wc * 64 + ni * 16 + pl) ^ wxor)] = acc[am][ni][rr];
        }
        asm volatile("" ::: "memory");
        __builtin_amdgcn_s_barrier();
        asm volatile("" ::: "memory");
#pragma unroll
        for (int rep = 0; rep < 4; ++rep) {
            int idx = rep * 512 + tid;
            int n = idx & 255, pq = idx >> 8;        // pq in [0,8)
            const float* vp = &epi[pq * 16 * 256];
            float v[15];
#pragma unroll
            for (int c = 0; c < 15; ++c) v[c] = vp[c * 256 + (n ^ (((c >> 2) & 1) << 4))];
            float val = v[0] + bias[n0 + n];
            float phi, s, pp;
            softplus_jet(val, phi, s, pp);
            float o[16];
            o[0] = phi;
            float d[4];
#pragma unroll
            for (int a = 0; a < 4; ++a) { d[a] = v[1 + a]; o[1 + a] = s * d[a]; }
            int ix = 5;
#pragma unroll
            for (int a = 0; a < 4; ++a)
#pragma unroll
                for (int b = a; b < 4; ++b) { o[ix] = pp * d[a] * d[b] + s * v[ix]; ++ix; }
            o[15] = 0.0f;
            size_t prow = (size_t)mt * 16 + h * 8 + pq;   // chunk-local point
            if (EPI == 1) {
                size_t rb = prow * 16 * 1024;
#pragma unroll
                for (int c = 0; c < 16; ++c) {
                    ushort_t hb, lb;
                    split_bf(o[c], hb, lb);
                    Anext[rb + (size_t)c * 1024 + n0 + n] = hb;
                    Anext[rb + (size_t)c * 1024 + 512 + n0 + n] = lb;
                }
            } else {
                float4* op = reinterpret_cast<float4*>(Sout + ((size_t)prow * 512 + n0 + n) * 16);
#pragma unroll
                for (int qq = 0; qq < 4; ++qq)
                    op[qq] = make_float4(o[4*qq], o[4*qq+1], o[4*qq+2], o[4*qq+3]);
            }
        }
    }
}

// ---------------- final layer + trace (validated) ----------------
__global__ __launch_bounds__(256) void trace_kernel(
    const float* __restrict__ Sin, const float* __restrict__ W3,
    const float* __restrict__ b3, float* __restrict__ out, int npts)
{
    int wave = threadIdx.x >> 6;
    int lane = threadIdx.x & 63;
    int p = blockIdx.x * 4 + wave;
    if (p >= npts) return;
    const float* sp = Sin + (size_t)p * (HDIM * NCH);

    float hu[4][10];
#pragma unroll
    for (int m = 0; m < 4; ++m)
#pragma unroll
        for (int qq = 0; qq < 10; ++qq) hu[m][qq] = 0.0f;
    float u4 = 0.0f;

    for (int kk = 0; kk < 8; ++kk) {
        int k = kk * 64 + lane;
        const float* sk = sp + k * NCH;
        float4 s0 = *reinterpret_cast<const float4*>(&sk[0]);
        float4 s1 = *reinterpret_cast<const float4*>(&sk[4]);
        float4 s2 = *reinterpret_cast<const float4*>(&sk[8]);
        float4 s3 = *reinterpret_cast<const float4*>(&sk[12]);
        float hv[10] = {s1.y,s1.z,s1.w, s2.x,s2.y,s2.z,s2.w, s3.x,s3.y,s3.z};
        float w3m[5];
#pragma unroll
        for (int m = 0; m < 5; ++m) w3m[m] = W3[m * HDIM + k];
        u4 = fmaf(w3m[4], s0.x, u4);
#pragma unroll
        for (int m = 0; m < 4; ++m)
#pragma unroll
            for (int qq = 0; qq < 10; ++qq) hu[m][qq] = fmaf(w3m[m], hv[qq], hu[m][qq]);
    }

#pragma unroll
    for (int off = 32; off > 0; off >>= 1) {
#pragma unroll
        for (int m = 0; m < 4; ++m)
#pragma unroll
            for (int qq = 0; qq < 10; ++qq) hu[m][qq] += __shfl_xor(hu[m][qq], off, 64);
        u4 += __shfl_xor(u4, off, 64);
    }

    if (lane == 0) {
        const int Pm[4][4] = {{0,1,2,3},{1,4,5,6},{2,5,7,8},{3,6,8,9}};
        const int Pd[4] = {0, 4, 7, 9};
#pragma unroll
        for (int i = 0; i < 4; ++i) {
            float t1 = hu[i][Pd[0]] + hu[i][Pd[1]] + hu[i][Pd[2]] + hu[i][Pd[3]];
            float t2 = hu[0][Pm[0][i]] + hu[1][Pm[1][i]] + hu[2][Pm[2][i]] + hu[3][Pm[3][i]];
            out[p * 5 + i] = t1 - t2;
        }
        out[p * 5 + 4] = u4 + b3[4];
    }
}

// ---------------- weight prep: W (n,k) -> BT[n][hi|lo|hi] bf16 ----------------
__global__ void prep_B(const float* __restrict__ W1, const float* __restrict__ W2,
                       ushort_t* __restrict__ BT1, ushort_t* __restrict__ BT2)
{
    int tid = blockIdx.x * 256 + threadIdx.x;   // 2*512*512 total
    int l = tid >> 18;
    int i = tid & 262143;
    int n = i >> 9, k = i & 511;
    const float* W = l ? W2 : W1;
    ushort_t* BT = l ? BT2 : BT1;
    float v = W[i];
    ushort_t hb, lb;
    split_bf(v, hb, lb);
    size_t rr = (size_t)n * KV;
    BT[rr + k] = hb;
    BT[rr + 512 + k] = lb;
    BT[rr + 1024 + k] = hb;
}

extern "C" void kernel_launch(void* const* d_in, const int* in_sizes, int n_in,
                              void* d_out, int out_size, void* d_ws, size_t ws_size,
                              hipStream_t stream)
{
    const float* x  = (const float*)d_in[0];
    const float* W0 = (const float*)d_in[1];
    const float* b0 = (const float*)d_in[2];
    const float* W1 = (const float*)d_in[3];
    const float* b1 = (const float*)d_in[4];
    const float* W2 = (const float*)d_in[5];
    const float* b2 = (const float*)d_in[6];
    const float* W3 = (const float*)d_in[7];
    const float* b3 = (const float*)d_in[8];
    float* out = (float*)d_out;

    int B = in_sizes[0] / 4;                    // 16384 points

    ushort_t* BT1 = (ushort_t*)d_ws;            // 512*1536 bf16
    ushort_t* BT2 = BT1 + 512 * KV;
    char* bufbase = (char*)(BT2 + 512 * KV);

    size_t avail = ws_size - 2ull * 512 * KV * sizeof(ushort_t);
    size_t per_pt = 2ull * 32768;               // A0/A1 buffers, 32KB each per point
    int Pc = (int)(avail / per_pt) & ~15;       // multiple of 16 (BM=256 = 16 points)
    if (Pc > 16384) Pc = 16384;
    if (Pc < 16) Pc = 16;

    ushort_t* A0 = (ushort_t*)bufbase;                        // Pc*16*1024
    ushort_t* A1 = (ushort_t*)(bufbase + (size_t)Pc * 32768);
    float* S2 = (float*)A0;                                   // reuse A0 after GEMM1

    prep_B<<<2048, 256, 0, stream>>>(W1, W2, BT1, BT2);

    for (int base = 0; base < B; base += Pc) {
        int np = (B - base < Pc) ? (B - base) : Pc;
        layer0_jet<<<np, 256, 0, stream>>>(x + (size_t)base * 4, W0, b0, A0);
        int nwg = (np / 16) * 2;                // (M/256) * (N/256)
        gemm_jet8<1><<<nwg, 512, 0, stream>>>(A0, BT1, b1, A1, nullptr);
        gemm_jet8<2><<<nwg, 512, 0, stream>>>(A1, BT2, b2, nullptr, S2);
        trace_kernel<<<(np + 3) / 4, 256, 0, stream>>>(S2, W3, b3, out + (size_t)base * 5, np);
    }
}